// Round 3
// baseline (1242.336 us; speedup 1.0000x reference)
//
#include <hip/hip_runtime.h>
#include <hip/hip_bf16.h>

// FreqMoE on MI355X. Round 11: 3 -> 2 kernels.
// (1) gi built by atomicAdd into persistent __device__ g_gi (zero-init at
//     module load; comb blocks re-zero it after the GEMM gate each iteration
//     -> self-resetting across graph replays, immune to ws poison). Kills
//     R10's 33x-redundant amag re-sum and the 16.8 MB amag store.
// (2) GEMM: 33 full-K blocks (i-tile 64, loop all f). No h atomics, no
//     h zero-fill. h written with device-scope atomic stores (cross-XCD
//     coherent). Runs co-resident with the expert FFTs.
// (3) k_mid + k_comb merged into k_rest (2344 blocks): GEMM first (p<33),
//     2048 expert iFFTs (XCD-grouped), 256 comb blocks last, gated on
//     g_gemm_done==33 (acquire spin). Deadlock-free: 256 spinners <<
//     resident capacity (~2048), producers at lowest blockIdx.
// Fixed floor in timed window: ws poison (~44us) + d_out poison (~23us).

using cplx = float2;
typedef float nfloat2 __attribute__((ext_vector_type(2)));

static constexpr int BB = 32, CCH = 8, LL = 4096, FF = 2049, EE = 8;

// workspace layout (float elements)
static constexpr size_t WS_FREQ  = 0;                                    // [256][2049] cplx
static constexpr size_t WS_MEAN  = WS_FREQ + (size_t)BB * CCH * FF * 2;  // 256
static constexpr size_t WS_SIGMA = WS_MEAN + 256;                        // 256
static constexpr size_t WS_H     = WS_SIGMA + 256;                       // 32*2049
static constexpr size_t WS_IDX   = WS_H + (size_t)BB * FF;               // 9 ints
static constexpr size_t WS_EOF   = WS_IDX + 16;                          // 2049 ints

// output layout (float elements), reference return order
static constexpr size_t OUT_COMB = 0;                                    // [32][8][4096]
static constexpr size_t OUT_BND  = (size_t)BB * CCH * LL;                // 9
static constexpr size_t OUT_GATE = OUT_BND + 9;                          // [32][8]
static constexpr size_t OUT_EXP  = OUT_GATE + (size_t)BB * EE;           // [32][8][8][4096] (odd float offset!)

// persistent module-static device memory: survives across launches, NOT
// poisoned by harness fills. g_gi/g_gemm_done/g_comb_fin are self-resetting
// each iteration (comb blocks restore them to 0 after use).
__device__ float2 g_W2048[2048];
__device__ float2 g_U[2049];
__device__ int    g_tabcnt = 0;        // reaches 17 once tables are built
__device__ float  g_gi[BB * FF];       // zero-init; += in k_fwd; zeroed by comb
__device__ int    g_gemm_done = 0;     // 33 when h is complete
__device__ int    g_comb_fin  = 0;     // reset chain

#define PHI(i) ((i) + ((i) >> 5))
__device__ __forceinline__ int scat(int n) {
  return ((n & 3) << 9) | (((n >> 2) & 7) << 6) | (((n >> 5) & 7) << 3) | (n >> 8);
}

template <bool INV>
__device__ __forceinline__ void dft8(float* zr, float* zi) {
  const float C = 0.70710678118654752f;
  float s0r = zr[0] + zr[4], s0i = zi[0] + zi[4];
  float d0r = zr[0] - zr[4], d0i = zi[0] - zi[4];
  float s1r = zr[2] + zr[6], s1i = zi[2] + zi[6];
  float d1r = zr[2] - zr[6], d1i = zi[2] - zi[6];
  float E0r = s0r + s1r, E0i = s0i + s1i;
  float E2r = s0r - s1r, E2i = s0i - s1i;
  float E1r, E1i, E3r, E3i;
  if (!INV) { E1r = d0r + d1i; E1i = d0i - d1r; E3r = d0r - d1i; E3i = d0i + d1r; }
  else      { E1r = d0r - d1i; E1i = d0i + d1r; E3r = d0r + d1i; E3i = d0i - d1r; }
  float t0r = zr[1] + zr[5], t0i = zi[1] + zi[5];
  float e0r = zr[1] - zr[5], e0i = zi[1] - zi[5];
  float t1r = zr[3] + zr[7], t1i = zi[3] + zi[7];
  float e1r = zr[3] - zr[7], e1i = zi[3] - zi[7];
  float O0r = t0r + t1r, O0i = t0i + t1i;
  float O2r = t0r - t1r, O2i = t0i - t1i;
  float O1r, O1i, O3r, O3i;
  if (!INV) { O1r = e0r + e1i; O1i = e0i - e1r; O3r = e0r - e1i; O3i = e0i + e1r; }
  else      { O1r = e0r - e1i; O1i = e0i + e1r; O3r = e0r + e1i; O3i = e0i - e1r; }
  float w1r, w1i, w2r, w2i, w3r, w3i;
  if (!INV) {
    w1r = C * (O1r + O1i); w1i = C * (O1i - O1r);
    w2r = O2i;             w2i = -O2r;
    w3r = C * (O3i - O3r); w3i = -C * (O3r + O3i);
  } else {
    w1r = C * (O1r - O1i); w1i = C * (O1i + O1r);
    w2r = -O2i;            w2i = O2r;
    w3r = -C * (O3r + O3i); w3i = C * (O3r - O3i);
  }
  zr[0] = E0r + O0r; zi[0] = E0i + O0i;
  zr[4] = E0r - O0r; zi[4] = E0i - O0i;
  zr[1] = E1r + w1r; zi[1] = E1i + w1i;
  zr[5] = E1r - w1r; zi[5] = E1i - w1i;
  zr[2] = E2r + w2r; zi[2] = E2i + w2i;
  zr[6] = E2r - w2r; zi[6] = E2i - w2i;
  zr[3] = E3r + w3r; zi[3] = E3i + w3i;
  zr[7] = E3r - w3r; zi[7] = E3i - w3i;
}

template <bool INV>
__device__ __forceinline__ void dft4(float* zr, float* zi) {
  float s0r = zr[0] + zr[2], s0i = zi[0] + zi[2];
  float d0r = zr[0] - zr[2], d0i = zi[0] - zi[2];
  float s1r = zr[1] + zr[3], s1i = zi[1] + zi[3];
  float d1r = zr[1] - zr[3], d1i = zi[1] - zi[3];
  zr[0] = s0r + s1r; zi[0] = s0i + s1i;
  zr[2] = s0r - s1r; zi[2] = s0i - s1i;
  if (!INV) { zr[1] = d0r + d1i; zi[1] = d0i - d1r; zr[3] = d0r - d1i; zi[3] = d0i + d1r; }
  else      { zr[1] = d0r - d1i; zi[1] = d0i + d1r; zr[3] = d0r + d1i; zi[3] = d0i - d1r; }
}

template <bool INV>
__device__ void fftr8(float* ZR, float* ZI, const cplx* __restrict__ W, int t) {
  float zr[8], zi[8];
  {
    int base = 8 * t;
#pragma unroll
    for (int m = 0; m < 8; ++m) { int i = PHI(base + m); zr[m] = ZR[i]; zi[m] = ZI[i]; }
    dft8<INV>(zr, zi);
#pragma unroll
    for (int m = 0; m < 8; ++m) { int i = PHI(base + m); ZR[i] = zr[m]; ZI[i] = zi[m]; }
  }
  __syncthreads();
  {
    int g = t & 31, p = t >> 5;
    int base = 64 * g + p;
#pragma unroll
    for (int m = 0; m < 8; ++m) { int i = PHI(base + 8 * m); zr[m] = ZR[i]; zi[m] = ZI[i]; }
#pragma unroll
    for (int m = 1; m < 8; ++m) {
      cplx w = W[32 * m * p];
      float wi = INV ? -w.y : w.y;
      float xr = zr[m] * w.x - zi[m] * wi;
      float xi = zr[m] * wi + zi[m] * w.x;
      zr[m] = xr; zi[m] = xi;
    }
    dft8<INV>(zr, zi);
#pragma unroll
    for (int m = 0; m < 8; ++m) { int i = PHI(base + 8 * m); ZR[i] = zr[m]; ZI[i] = zi[m]; }
  }
  __syncthreads();
  {
    int g = t & 3, p = t >> 2;
    int base = 512 * g + p;
#pragma unroll
    for (int m = 0; m < 8; ++m) { int i = PHI(base + 64 * m); zr[m] = ZR[i]; zi[m] = ZI[i]; }
#pragma unroll
    for (int m = 1; m < 8; ++m) {
      cplx w = W[4 * m * p];
      float wi = INV ? -w.y : w.y;
      float xr = zr[m] * w.x - zi[m] * wi;
      float xi = zr[m] * wi + zi[m] * w.x;
      zr[m] = xr; zi[m] = xi;
    }
    dft8<INV>(zr, zi);
#pragma unroll
    for (int m = 0; m < 8; ++m) { int i = PHI(base + 64 * m); ZR[i] = zr[m]; ZI[i] = zi[m]; }
  }
  __syncthreads();
  {
#pragma unroll
    for (int h = 0; h < 2; ++h) {
      int p = t + (h << 8);
      float yr[4], yi[4];
#pragma unroll
      for (int m = 0; m < 4; ++m) { int i = PHI(p + 512 * m); yr[m] = ZR[i]; yi[m] = ZI[i]; }
#pragma unroll
      for (int m = 1; m < 4; ++m) {
        cplx w = W[m * p];
        float wi = INV ? -w.y : w.y;
        float xr = yr[m] * w.x - yi[m] * wi;
        float xi = yr[m] * wi + yi[m] * w.x;
        yr[m] = xr; yi[m] = xi;
      }
      dft4<INV>(yr, yi);
#pragma unroll
      for (int m = 0; m < 4; ++m) { int i = PHI(p + 512 * m); ZR[i] = yr[m]; ZI[i] = yi[m]; }
    }
  }
  __syncthreads();
}

// shared expert-irfft body
__device__ __forceinline__ void expert_ifft(const float* __restrict__ ws,
                                            float* __restrict__ out,
                                            float* ZR, float* ZI,
                                            int bc, int j, int t) {
  const int b = bc >> 3, c = bc & 7;
  const cplx* freq = (const cplx*)ws + (size_t)bc * FF;
  const int*  idxp = (const int*)(ws + WS_IDX);
  const int lo = idxp[j], hi = idxp[j + 1];

#pragma unroll
  for (int u = 0; u < 8; ++u) {
    int k  = t + (u << 8);
    int km = 2048 - k;
    cplx A = make_float2(0.f, 0.f), Bv = make_float2(0.f, 0.f);
    if (k >= lo && k < hi)   A  = freq[k];
    if (km >= lo && km < hi) Bv = freq[km];
    float Px = A.x - Bv.x, Py = A.y + Bv.y;
    float Qx = A.x + Bv.x, Qy = A.y - Bv.y;
    cplx uk = g_U[k];
    float cs = uk.x, sn = -uk.y;
    float Xox = 0.5f * (cs * Px - sn * Py);
    float Xoy = 0.5f * (cs * Py + sn * Px);
    int i = PHI(scat(k));
    ZR[i] = 0.5f * Qx - Xoy;
    ZI[i] = 0.5f * Qy + Xox;
  }
  __syncthreads();

  fftr8<true>(ZR, ZI, g_W2048, t);

  // expert row: odd-aligned base. o[2n]=ZR[n], o[2n+1]=ZI[n]. Pair shift:
  // scalar o[0]; pairs (o[2n+1],o[2n+2])=(ZI[n],ZR[n+1]) at odd elem idx
  // (even absolute float idx -> 8B aligned); scalar o[4095]=ZI[2047].
  const float mul = 1.0f / 2048.0f;
  float* op = out + OUT_EXP + (((size_t)(b * EE + j) * CCH + c) * LL);
  if (t == 0) __builtin_nontemporal_store(ZR[PHI(0)] * mul, op);
#pragma unroll
  for (int u = 0; u < 8; ++u) {
    int n = t + (u << 8);
    if (n < 2047) {
      nfloat2 o;
      o.x = ZI[PHI(n)] * mul;
      o.y = ZR[PHI(n + 1)] * mul;
      __builtin_nontemporal_store(o, (nfloat2*)(op + 2 * n + 1));
    } else {
      __builtin_nontemporal_store(ZI[PHI(2047)] * mul, op + 4095);
    }
  }
}

// ---------------- kernel 1: stats + normalize + rfft(4096) + gi(atomic)
//                  + spare blocks: tables (iter 0) / idx+eof ------------------
__global__ __launch_bounds__(256) void k_fwd(const float* __restrict__ x,
                                             const float* __restrict__ raw,
                                             float* __restrict__ ws,
                                             float* __restrict__ out) {
  const int p = blockIdx.x, t = threadIdx.x;

  if (p >= 256) {
    if (p < 273) {
      // persistent tables, computed once per process (flag skips after)
      if (__hip_atomic_load(&g_tabcnt, __ATOMIC_RELAXED, __HIP_MEMORY_SCOPE_AGENT) < 17) {
        if (p < 264) {
          int jj = (p - 256) * 256 + t;
          float sn, cs;
          sincosf(-6.283185307179586f * (float)jj / 2048.0f, &sn, &cs);
          g_W2048[jj] = make_float2(cs, sn);
        } else {
          int k = (p - 264) * 256 + t;
          if (k < FF) {
            float sn, cs;
            sincosf(-3.14159265358979323846f * (float)k / 2048.0f, &sn, &cs);
            g_U[k] = make_float2(cs, sn);
          }
        }
        __syncthreads();
        if (t == 0) {
          __threadfence();
          __hip_atomic_fetch_add(&g_tabcnt, 1, __ATOMIC_RELEASE, __HIP_MEMORY_SCOPE_AGENT);
        }
      }
    } else {
      // boundaries/idx/eof (input-dependent, every iter)
      __shared__ int idx_s[9];
      if (t == 0) {
        float v[7];
        for (int i = 0; i < 7; ++i) v[i] = 1.0f / (1.0f + expf(-raw[i]));
        for (int a = 1; a < 7; ++a) {
          float key = v[a];
          int q = a - 1;
          while (q >= 0 && v[q] > key) { v[q + 1] = v[q]; --q; }
          v[q + 1] = key;
        }
        float bnd[9];
        bnd[0] = 0.0f; bnd[8] = 1.0f;
        for (int i = 0; i < 7; ++i) bnd[i + 1] = v[i];
        int* wi = (int*)(ws + WS_IDX);
        for (int e = 0; e < 9; ++e) {
          int id = (int)floorf(bnd[e] * (float)FF);
          if (e == 8) id = FF;
          idx_s[e] = id;
          wi[e] = id;
          out[OUT_BND + e] = bnd[e];
        }
      }
      __syncthreads();
      int* eof = (int*)(ws + WS_EOF);
      for (int f = t; f < FF; f += 256) {
        int e = 0;
        for (int q = 1; q < 8; ++q)
          if (f >= idx_s[q]) e = q;
        eof[f] = e;
      }
    }
    return;
  }

  __shared__ float ZR[2112], ZI[2112];
  __shared__ float red[8];
  const int bc = p;
  const int b  = bc >> 3;
  const int lane = t & 63, wid = t >> 6;
  const float2* xp2 = (const float2*)(x + (size_t)bc * LL);

  float2 v[8];
  float sum = 0.f;
#pragma unroll
  for (int u = 0; u < 8; ++u) {
    v[u] = xp2[t + (u << 8)];
    sum += v[u].x + v[u].y;
  }
#pragma unroll
  for (int off = 32; off > 0; off >>= 1) sum += __shfl_down(sum, off, 64);
  if (lane == 0) red[wid] = sum;
  __syncthreads();
  const float mean = (red[0] + red[1] + red[2] + red[3]) * (1.0f / 4096.0f);

  float ss = 0.f;
#pragma unroll
  for (int u = 0; u < 8; ++u) {
    float dx = v[u].x - mean, dy = v[u].y - mean;
    ss += dx * dx + dy * dy;
  }
#pragma unroll
  for (int off = 32; off > 0; off >>= 1) ss += __shfl_down(ss, off, 64);
  if (lane == 0) red[4 + wid] = ss;
  __syncthreads();
  const float var   = (red[4] + red[5] + red[6] + red[7]) / 4095.0f + 1e-5f;
  const float sigma = sqrtf(var);
  const float inv   = 1.0f / sigma;
  if (t == 0) {
    ws[WS_MEAN + bc]  = mean;
    ws[WS_SIGMA + bc] = sigma;
  }

#pragma unroll
  for (int u = 0; u < 8; ++u) {
    int n = t + (u << 8);
    int i = PHI(scat(n));
    ZR[i] = (v[u].x - mean) * inv;
    ZI[i] = (v[u].y - mean) * inv;
  }
  // wait for twiddle tables (only ever spins on the very first execution)
  if (t == 0) {
    while (__hip_atomic_load(&g_tabcnt, __ATOMIC_ACQUIRE, __HIP_MEMORY_SCOPE_AGENT) < 17) {
      __builtin_amdgcn_s_sleep(8);
    }
  }
  __syncthreads();

  fftr8<false>(ZR, ZI, g_W2048, t);

  cplx* freq = (cplx*)ws + (size_t)bc * FF;
#pragma unroll
  for (int u = 0; u < 9; ++u) {
    int k = t + (u << 8);
    if (k > 2048) break;
    int ka = k & 2047, km = (2048 - k) & 2047;
    float Zkr = ZR[PHI(ka)], Zki = ZI[PHI(ka)];
    float Zmr = ZR[PHI(km)], Zmi = ZI[PHI(km)];
    float fex = 0.5f * (Zkr + Zmr);
    float fey = 0.5f * (Zki - Zmi);
    float fox = 0.5f * (Zki + Zmi);
    float foy = -0.5f * (Zkr - Zmr);
    cplx uk = g_U[k];
    float rx = fex + uk.x * fox - uk.y * foy;
    float ry = fey + uk.x * foy + uk.y * fox;
    freq[k] = make_float2(rx, ry);
    atomicAdd(&g_gi[(size_t)b * FF + k], 0.125f * sqrtf(rx * rx + ry * ry));
  }
}

// ---------------- kernel 2: GEMM(33) + expert irffts(2048) + comb(256) ------
__global__ __launch_bounds__(256) void k_rest(const float* __restrict__ W1,
                                              const float* __restrict__ b1,
                                              const float* __restrict__ W2,
                                              const float* __restrict__ b2,
                                              float* __restrict__ ws,
                                              float* __restrict__ out) {
  __shared__ float SM[4224];
  __shared__ float red[4][8];
  __shared__ float lg[8];
  __shared__ float gates_s[8];
  const int p = blockIdx.x, t = threadIdx.x;

  if (p < 33) {
    // ---- full-K GEMM: h[b][i0:i0+64] = sum_f gi[b][f] * W1[i][f] ----
    float* W1s = SM;          // [64][33]
    float* gis = SM + 2112;   // [32][33]
    const int i0 = p * 64;
    const int il = t & 63, bg = t >> 6;
    float acc[8] = {0, 0, 0, 0, 0, 0, 0, 0};
    for (int f0 = 0; f0 < FF; f0 += 32) {
      for (int q = t; q < 64 * 32; q += 256) {
        int r = q >> 5, cc = q & 31;
        int gi_i = i0 + r, gf = f0 + cc;
        W1s[r * 33 + cc] = (gi_i < FF && gf < FF) ? W1[(size_t)gi_i * FF + gf] : 0.f;
      }
      for (int q = t; q < 32 * 32; q += 256) {
        int bb = q >> 5, cc = q & 31;
        int gf = f0 + cc;
        gis[bb * 33 + cc] = (gf < FF) ? g_gi[(size_t)bb * FF + gf] : 0.f;
      }
      __syncthreads();
#pragma unroll 8
      for (int cc = 0; cc < 32; ++cc) {
        float wv = W1s[il * 33 + cc];
#pragma unroll
        for (int j = 0; j < 8; ++j) acc[j] += wv * gis[(bg * 8 + j) * 33 + cc];
      }
      __syncthreads();
    }
    int ii = i0 + il;
    if (ii < FF) {
#pragma unroll
      for (int j = 0; j < 8; ++j)
        __hip_atomic_store(&ws[WS_H + (size_t)(bg * 8 + j) * FF + ii], acc[j],
                           __ATOMIC_RELAXED, __HIP_MEMORY_SCOPE_AGENT);
    }
    __syncthreads();
    if (t == 0) {
      __threadfence();
      __hip_atomic_fetch_add(&g_gemm_done, 1, __ATOMIC_RELEASE, __HIP_MEMORY_SCOPE_AGENT);
    }
    return;
  }
  if (p < 40) return;  // pad so expert range starts at a multiple of 8

  if (p < 2088) {
    // experts j=0..7, XCD-grouped: blk%8 == bc%8 == freq-writer XCD
    const int e   = p - 40;             // 0..2047
    const int xcd = e & 7, s = e >> 3;  // s in [0,256)
    const int grp = s >> 3, j = s & 7;
    const int bc  = (grp << 3) | xcd;
    expert_ifft(ws, out, SM, SM + 2112, bc, j, t);
    return;
  }

  // ---- comb: gate on h, zero g_gi, logits+softmax, combined irfft ----
  const int q  = p - 2088;   // 0..255; (2088%8==0 so p%8 == q%8 == bc%8)
  const int bc = q;
  const int b  = bc >> 3, c = bc & 7;
  const int lane = t & 63, wid = t >> 6;
  float* ZR = SM;
  float* ZI = SM + 2112;

  if (t == 0) {
    while (__hip_atomic_load(&g_gemm_done, __ATOMIC_ACQUIRE, __HIP_MEMORY_SCOPE_AGENT) < 33) {
      __builtin_amdgcn_s_sleep(2);
    }
  }
  __syncthreads();

  // zero g_gi for the next iteration (GEMM readers are all done)
  {
    int i = q * 256 + t;
    g_gi[i] = 0.f;
    if (i < 32) g_gi[65536 + i] = 0.f;  // 32*2049 = 65568
  }

  // logits for batch b (redundant across the 8 c-blocks; ~64 FMA/thread)
  float pacc[8] = {0, 0, 0, 0, 0, 0, 0, 0};
  const float* hrow = ws + WS_H + (size_t)b * FF;
  for (int f = t; f < FF; f += 256) {
    float hv = __hip_atomic_load(&hrow[f], __ATOMIC_RELAXED, __HIP_MEMORY_SCOPE_AGENT);
    hv = fmaxf(hv + b1[f], 0.f);
#pragma unroll
    for (int e = 0; e < 8; ++e) pacc[e] += hv * W2[(size_t)e * FF + f];
  }
#pragma unroll
  for (int off = 32; off > 0; off >>= 1) {
#pragma unroll
    for (int e = 0; e < 8; ++e) pacc[e] += __shfl_down(pacc[e], off, 64);
  }
  if (lane == 0) {
#pragma unroll
    for (int e = 0; e < 8; ++e) red[wid][e] = pacc[e];
  }
  __syncthreads();
  if (t < 8) lg[t] = red[0][t] + red[1][t] + red[2][t] + red[3][t] + b2[t];
  __syncthreads();
  if (t < 8) {
    float mx = lg[0];
#pragma unroll
    for (int r2 = 1; r2 < 8; ++r2) mx = fmaxf(mx, lg[r2]);
    float sm = 0.f;
#pragma unroll
    for (int r2 = 0; r2 < 8; ++r2) sm += expf(lg[r2] - mx);
    float g = expf(lg[t] - mx) / sm;
    gates_s[t] = g;
    if (c == 0) out[OUT_GATE + (size_t)b * 8 + t] = g;
  }
  __syncthreads();

  const cplx* freq = (const cplx*)ws + (size_t)bc * FF;
  const int*  eof  = (const int*)(ws + WS_EOF);

#pragma unroll
  for (int u = 0; u < 8; ++u) {
    int k  = t + (u << 8);
    int km = 2048 - k;
    cplx A  = freq[k];
    cplx Bv = freq[km];
    float gk = gates_s[eof[k]], gm = gates_s[eof[km]];
    A.x *= gk; A.y *= gk; Bv.x *= gm; Bv.y *= gm;
    float Px = A.x - Bv.x, Py = A.y + Bv.y;
    float Qx = A.x + Bv.x, Qy = A.y - Bv.y;
    cplx uk = g_U[k];
    float cs = uk.x, sn = -uk.y;
    float Xox = 0.5f * (cs * Px - sn * Py);
    float Xoy = 0.5f * (cs * Py + sn * Px);
    int i = PHI(scat(k));
    ZR[i] = 0.5f * Qx - Xoy;
    ZI[i] = 0.5f * Qy + Xox;
  }
  __syncthreads();

  fftr8<true>(ZR, ZI, g_W2048, t);

  const float mul = ws[WS_SIGMA + bc] * (1.0f / 2048.0f);
  const float add = ws[WS_MEAN + bc];
  nfloat2* op = (nfloat2*)(out + OUT_COMB + (size_t)bc * LL);
#pragma unroll
  for (int u = 0; u < 8; ++u) {
    int n = t + (u << 8);
    nfloat2 o;
    o.x = ZR[PHI(n)] * mul + add;
    o.y = ZI[PHI(n)] * mul + add;
    __builtin_nontemporal_store(o, op + n);
  }

  // self-reset counters for the next iteration / graph replay
  if (t == 0) {
    int r2 = __hip_atomic_fetch_add(&g_comb_fin, 1, __ATOMIC_ACQ_REL, __HIP_MEMORY_SCOPE_AGENT);
    if (r2 == 255) {
      __hip_atomic_store(&g_gemm_done, 0, __ATOMIC_RELAXED, __HIP_MEMORY_SCOPE_AGENT);
      __hip_atomic_store(&g_comb_fin, 0, __ATOMIC_RELAXED, __HIP_MEMORY_SCOPE_AGENT);
    }
  }
}

extern "C" void kernel_launch(void* const* d_in, const int* in_sizes, int n_in,
                              void* d_out, int out_size, void* d_ws, size_t ws_size,
                              hipStream_t stream) {
  const float* x   = (const float*)d_in[0];
  const float* raw = (const float*)d_in[1];
  const float* W1  = (const float*)d_in[2];
  const float* b1  = (const float*)d_in[3];
  const float* W2  = (const float*)d_in[4];
  const float* b2  = (const float*)d_in[5];
  float* out = (float*)d_out;
  float* ws  = (float*)d_ws;

  k_fwd<<<274, 256, 0, stream>>>(x, raw, ws, out);
  k_rest<<<2344, 256, 0, stream>>>(W1, b1, W2, b2, ws, out);
}

// Round 4
// 130.627 us; speedup vs baseline: 9.5106x; 9.5106x over previous
//
#include <hip/hip_runtime.h>
#include <hip/hip_bf16.h>

// FreqMoE on MI355X. Round 12: recover from R11's spin-gate catastrophe.
// Structure = proven R9 (134.8us) minus the k_misc dispatch, with NO
// intra-kernel gates (R11's comb spin-wait on g_gemm_done stalled the whole
// dispatch at 0.5% HBM / 1.3% VALU for ~1.2ms -- producer/spinner scheduling
// pathology; all cross-stage edges are kernel boundaries again).
// - Persistent __device__ twiddle tables (built once, flag-skipped after).
// - k_fwd: 256 FFT blocks atomicAdd gi into persistent g_gi (proven fast in
//   R11); spare blocks: tables (iter 0), idx/eof, zero-h.
// - k_mid: R9's K-split GEMM (1089 blocks, h-atomicAdd, gis staged straight
//   from g_gi -- single read/element) + 2048 XCD-grouped expert iFFTs.
// - k_comb: zeroes g_gi for next iteration (GEMM consumed it last dispatch),
//   then logits+softmax+combined iFFT (256 blocks).
// Fixed floor in timed window: ws poison (~44us) + d_out poison (~23us).

using cplx = float2;
typedef float nfloat2 __attribute__((ext_vector_type(2)));

static constexpr int BB = 32, CCH = 8, LL = 4096, FF = 2049, EE = 8;

// workspace layout (float elements)
static constexpr size_t WS_FREQ  = 0;                                    // [256][2049] cplx
static constexpr size_t WS_MEAN  = WS_FREQ + (size_t)BB * CCH * FF * 2;  // 256
static constexpr size_t WS_SIGMA = WS_MEAN + 256;                        // 256
static constexpr size_t WS_H     = WS_SIGMA + 256;                       // 32*2049
static constexpr size_t WS_IDX   = WS_H + (size_t)BB * FF;               // 9 ints
static constexpr size_t WS_EOF   = WS_IDX + 16;                          // 2049 ints

// output layout (float elements), reference return order
static constexpr size_t OUT_COMB = 0;                                    // [32][8][4096]
static constexpr size_t OUT_BND  = (size_t)BB * CCH * LL;                // 9
static constexpr size_t OUT_GATE = OUT_BND + 9;                          // [32][8]
static constexpr size_t OUT_EXP  = OUT_GATE + (size_t)BB * EE;           // [32][8][8][4096] (odd float offset!)

// persistent module-static device memory: survives across launches, NOT
// poisoned by harness fills. g_gi is zeroed by k_comb each iteration (its
// consumer, k_mid's GEMM, completed at the prior kernel boundary).
__device__ float2 g_W2048[2048];
__device__ float2 g_U[2049];
__device__ int    g_tabcnt = 0;        // reaches 17 once tables are built
__device__ float  g_gi[BB * FF];       // zero-init; += in k_fwd; zeroed in k_comb

#define PHI(i) ((i) + ((i) >> 5))
__device__ __forceinline__ int scat(int n) {
  return ((n & 3) << 9) | (((n >> 2) & 7) << 6) | (((n >> 5) & 7) << 3) | (n >> 8);
}

template <bool INV>
__device__ __forceinline__ void dft8(float* zr, float* zi) {
  const float C = 0.70710678118654752f;
  float s0r = zr[0] + zr[4], s0i = zi[0] + zi[4];
  float d0r = zr[0] - zr[4], d0i = zi[0] - zi[4];
  float s1r = zr[2] + zr[6], s1i = zi[2] + zi[6];
  float d1r = zr[2] - zr[6], d1i = zi[2] - zi[6];
  float E0r = s0r + s1r, E0i = s0i + s1i;
  float E2r = s0r - s1r, E2i = s0i - s1i;
  float E1r, E1i, E3r, E3i;
  if (!INV) { E1r = d0r + d1i; E1i = d0i - d1r; E3r = d0r - d1i; E3i = d0i + d1r; }
  else      { E1r = d0r - d1i; E1i = d0i + d1r; E3r = d0r + d1i; E3i = d0i - d1r; }
  float t0r = zr[1] + zr[5], t0i = zi[1] + zi[5];
  float e0r = zr[1] - zr[5], e0i = zi[1] - zi[5];
  float t1r = zr[3] + zr[7], t1i = zi[3] + zi[7];
  float e1r = zr[3] - zr[7], e1i = zi[3] - zi[7];
  float O0r = t0r + t1r, O0i = t0i + t1i;
  float O2r = t0r - t1r, O2i = t0i - t1i;
  float O1r, O1i, O3r, O3i;
  if (!INV) { O1r = e0r + e1i; O1i = e0i - e1r; O3r = e0r - e1i; O3i = e0i + e1r; }
  else      { O1r = e0r - e1i; O1i = e0i + e1r; O3r = e0r + e1i; O3i = e0i - e1r; }
  float w1r, w1i, w2r, w2i, w3r, w3i;
  if (!INV) {
    w1r = C * (O1r + O1i); w1i = C * (O1i - O1r);
    w2r = O2i;             w2i = -O2r;
    w3r = C * (O3i - O3r); w3i = -C * (O3r + O3i);
  } else {
    w1r = C * (O1r - O1i); w1i = C * (O1i + O1r);
    w2r = -O2i;            w2i = O2r;
    w3r = -C * (O3r + O3i); w3i = C * (O3r - O3i);
  }
  zr[0] = E0r + O0r; zi[0] = E0i + O0i;
  zr[4] = E0r - O0r; zi[4] = E0i - O0i;
  zr[1] = E1r + w1r; zi[1] = E1i + w1i;
  zr[5] = E1r - w1r; zi[5] = E1i - w1i;
  zr[2] = E2r + w2r; zi[2] = E2i + w2i;
  zr[6] = E2r - w2r; zi[6] = E2i - w2i;
  zr[3] = E3r + w3r; zi[3] = E3i + w3i;
  zr[7] = E3r - w3r; zi[7] = E3i - w3i;
}

template <bool INV>
__device__ __forceinline__ void dft4(float* zr, float* zi) {
  float s0r = zr[0] + zr[2], s0i = zi[0] + zi[2];
  float d0r = zr[0] - zr[2], d0i = zi[0] - zi[2];
  float s1r = zr[1] + zr[3], s1i = zi[1] + zi[3];
  float d1r = zr[1] - zr[3], d1i = zi[1] - zi[3];
  zr[0] = s0r + s1r; zi[0] = s0i + s1i;
  zr[2] = s0r - s1r; zi[2] = s0i - s1i;
  if (!INV) { zr[1] = d0r + d1i; zi[1] = d0i - d1r; zr[3] = d0r - d1i; zi[3] = d0i + d1r; }
  else      { zr[1] = d0r - d1i; zi[1] = d0i + d1r; zr[3] = d0r + d1i; zi[3] = d0i - d1r; }
}

template <bool INV>
__device__ void fftr8(float* ZR, float* ZI, const cplx* __restrict__ W, int t) {
  float zr[8], zi[8];
  {
    int base = 8 * t;
#pragma unroll
    for (int m = 0; m < 8; ++m) { int i = PHI(base + m); zr[m] = ZR[i]; zi[m] = ZI[i]; }
    dft8<INV>(zr, zi);
#pragma unroll
    for (int m = 0; m < 8; ++m) { int i = PHI(base + m); ZR[i] = zr[m]; ZI[i] = zi[m]; }
  }
  __syncthreads();
  {
    int g = t & 31, p = t >> 5;
    int base = 64 * g + p;
#pragma unroll
    for (int m = 0; m < 8; ++m) { int i = PHI(base + 8 * m); zr[m] = ZR[i]; zi[m] = ZI[i]; }
#pragma unroll
    for (int m = 1; m < 8; ++m) {
      cplx w = W[32 * m * p];
      float wi = INV ? -w.y : w.y;
      float xr = zr[m] * w.x - zi[m] * wi;
      float xi = zr[m] * wi + zi[m] * w.x;
      zr[m] = xr; zi[m] = xi;
    }
    dft8<INV>(zr, zi);
#pragma unroll
    for (int m = 0; m < 8; ++m) { int i = PHI(base + 8 * m); ZR[i] = zr[m]; ZI[i] = zi[m]; }
  }
  __syncthreads();
  {
    int g = t & 3, p = t >> 2;
    int base = 512 * g + p;
#pragma unroll
    for (int m = 0; m < 8; ++m) { int i = PHI(base + 64 * m); zr[m] = ZR[i]; zi[m] = ZI[i]; }
#pragma unroll
    for (int m = 1; m < 8; ++m) {
      cplx w = W[4 * m * p];
      float wi = INV ? -w.y : w.y;
      float xr = zr[m] * w.x - zi[m] * wi;
      float xi = zr[m] * wi + zi[m] * w.x;
      zr[m] = xr; zi[m] = xi;
    }
    dft8<INV>(zr, zi);
#pragma unroll
    for (int m = 0; m < 8; ++m) { int i = PHI(base + 64 * m); ZR[i] = zr[m]; ZI[i] = zi[m]; }
  }
  __syncthreads();
  {
#pragma unroll
    for (int h = 0; h < 2; ++h) {
      int p = t + (h << 8);
      float yr[4], yi[4];
#pragma unroll
      for (int m = 0; m < 4; ++m) { int i = PHI(p + 512 * m); yr[m] = ZR[i]; yi[m] = ZI[i]; }
#pragma unroll
      for (int m = 1; m < 4; ++m) {
        cplx w = W[m * p];
        float wi = INV ? -w.y : w.y;
        float xr = yr[m] * w.x - yi[m] * wi;
        float xi = yr[m] * wi + yi[m] * w.x;
        yr[m] = xr; yi[m] = xi;
      }
      dft4<INV>(yr, yi);
#pragma unroll
      for (int m = 0; m < 4; ++m) { int i = PHI(p + 512 * m); ZR[i] = yr[m]; ZI[i] = yi[m]; }
    }
  }
  __syncthreads();
}

// shared expert-irfft body
__device__ __forceinline__ void expert_ifft(const float* __restrict__ ws,
                                            float* __restrict__ out,
                                            float* ZR, float* ZI,
                                            int bc, int j, int t) {
  const int b = bc >> 3, c = bc & 7;
  const cplx* freq = (const cplx*)ws + (size_t)bc * FF;
  const int*  idxp = (const int*)(ws + WS_IDX);
  const int lo = idxp[j], hi = idxp[j + 1];

#pragma unroll
  for (int u = 0; u < 8; ++u) {
    int k  = t + (u << 8);
    int km = 2048 - k;
    cplx A = make_float2(0.f, 0.f), Bv = make_float2(0.f, 0.f);
    if (k >= lo && k < hi)   A  = freq[k];
    if (km >= lo && km < hi) Bv = freq[km];
    float Px = A.x - Bv.x, Py = A.y + Bv.y;
    float Qx = A.x + Bv.x, Qy = A.y - Bv.y;
    cplx uk = g_U[k];
    float cs = uk.x, sn = -uk.y;
    float Xox = 0.5f * (cs * Px - sn * Py);
    float Xoy = 0.5f * (cs * Py + sn * Px);
    int i = PHI(scat(k));
    ZR[i] = 0.5f * Qx - Xoy;
    ZI[i] = 0.5f * Qy + Xox;
  }
  __syncthreads();

  fftr8<true>(ZR, ZI, g_W2048, t);

  // expert row: odd-aligned base. o[2n]=ZR[n], o[2n+1]=ZI[n]. Pair shift:
  // scalar o[0]; pairs (o[2n+1],o[2n+2])=(ZI[n],ZR[n+1]) at odd elem idx
  // (even absolute float idx -> 8B aligned); scalar o[4095]=ZI[2047].
  const float mul = 1.0f / 2048.0f;
  float* op = out + OUT_EXP + (((size_t)(b * EE + j) * CCH + c) * LL);
  if (t == 0) __builtin_nontemporal_store(ZR[PHI(0)] * mul, op);
#pragma unroll
  for (int u = 0; u < 8; ++u) {
    int n = t + (u << 8);
    if (n < 2047) {
      nfloat2 o;
      o.x = ZI[PHI(n)] * mul;
      o.y = ZR[PHI(n + 1)] * mul;
      __builtin_nontemporal_store(o, (nfloat2*)(op + 2 * n + 1));
    } else {
      __builtin_nontemporal_store(ZI[PHI(2047)] * mul, op + 4095);
    }
  }
}

// ---------------- kernel 1: stats + normalize + rfft(4096) + gi(atomic)
//                  + spares: tables (iter 0) / idx+eof / zero-h --------------
__global__ __launch_bounds__(256) void k_fwd(const float* __restrict__ x,
                                             const float* __restrict__ raw,
                                             float* __restrict__ ws,
                                             float* __restrict__ out) {
  const int p = blockIdx.x, t = threadIdx.x;

  if (p >= 256) {
    if (p < 273) {
      // persistent tables, computed once per process (flag skips after)
      if (__hip_atomic_load(&g_tabcnt, __ATOMIC_RELAXED, __HIP_MEMORY_SCOPE_AGENT) < 17) {
        if (p < 264) {
          int jj = (p - 256) * 256 + t;
          float sn, cs;
          sincosf(-6.283185307179586f * (float)jj / 2048.0f, &sn, &cs);
          g_W2048[jj] = make_float2(cs, sn);
        } else {
          int k = (p - 264) * 256 + t;
          if (k < FF) {
            float sn, cs;
            sincosf(-3.14159265358979323846f * (float)k / 2048.0f, &sn, &cs);
            g_U[k] = make_float2(cs, sn);
          }
        }
        __syncthreads();
        if (t == 0) {
          __threadfence();
          __hip_atomic_fetch_add(&g_tabcnt, 1, __ATOMIC_RELEASE, __HIP_MEMORY_SCOPE_AGENT);
        }
      }
    } else if (p == 273) {
      // boundaries/idx/eof (input-dependent, every iter)
      __shared__ int idx_s[9];
      if (t == 0) {
        float v[7];
        for (int i = 0; i < 7; ++i) v[i] = 1.0f / (1.0f + expf(-raw[i]));
        for (int a = 1; a < 7; ++a) {
          float key = v[a];
          int q = a - 1;
          while (q >= 0 && v[q] > key) { v[q + 1] = v[q]; --q; }
          v[q + 1] = key;
        }
        float bnd[9];
        bnd[0] = 0.0f; bnd[8] = 1.0f;
        for (int i = 0; i < 7; ++i) bnd[i + 1] = v[i];
        int* wi = (int*)(ws + WS_IDX);
        for (int e = 0; e < 9; ++e) {
          int id = (int)floorf(bnd[e] * (float)FF);
          if (e == 8) id = FF;
          idx_s[e] = id;
          wi[e] = id;
          out[OUT_BND + e] = bnd[e];
        }
      }
      __syncthreads();
      int* eof = (int*)(ws + WS_EOF);
      for (int f = t; f < FF; f += 256) {
        int e = 0;
        for (int q = 1; q < 8; ++q)
          if (f >= idx_s[q]) e = q;
        eof[f] = e;
      }
    } else {
      // zero h: 65568 floats = 16392 float4, 8 blocks (consumed by k_mid)
      float4* hp = (float4*)(ws + WS_H);
      const float4 z4 = make_float4(0.f, 0.f, 0.f, 0.f);
      for (int i = (p - 274) * 256 + t; i < 16392; i += 8 * 256) hp[i] = z4;
    }
    return;
  }

  __shared__ float ZR[2112], ZI[2112];
  __shared__ float red[8];
  const int bc = p;
  const int b  = bc >> 3;
  const int lane = t & 63, wid = t >> 6;
  const float2* xp2 = (const float2*)(x + (size_t)bc * LL);

  float2 v[8];
  float sum = 0.f;
#pragma unroll
  for (int u = 0; u < 8; ++u) {
    v[u] = xp2[t + (u << 8)];
    sum += v[u].x + v[u].y;
  }
#pragma unroll
  for (int off = 32; off > 0; off >>= 1) sum += __shfl_down(sum, off, 64);
  if (lane == 0) red[wid] = sum;
  __syncthreads();
  const float mean = (red[0] + red[1] + red[2] + red[3]) * (1.0f / 4096.0f);

  float ss = 0.f;
#pragma unroll
  for (int u = 0; u < 8; ++u) {
    float dx = v[u].x - mean, dy = v[u].y - mean;
    ss += dx * dx + dy * dy;
  }
#pragma unroll
  for (int off = 32; off > 0; off >>= 1) ss += __shfl_down(ss, off, 64);
  if (lane == 0) red[4 + wid] = ss;
  __syncthreads();
  const float var   = (red[4] + red[5] + red[6] + red[7]) / 4095.0f + 1e-5f;
  const float sigma = sqrtf(var);
  const float inv   = 1.0f / sigma;
  if (t == 0) {
    ws[WS_MEAN + bc]  = mean;
    ws[WS_SIGMA + bc] = sigma;
  }

#pragma unroll
  for (int u = 0; u < 8; ++u) {
    int n = t + (u << 8);
    int i = PHI(scat(n));
    ZR[i] = (v[u].x - mean) * inv;
    ZI[i] = (v[u].y - mean) * inv;
  }
  // wait for twiddle tables (only ever spins on the very first execution)
  if (t == 0) {
    while (__hip_atomic_load(&g_tabcnt, __ATOMIC_ACQUIRE, __HIP_MEMORY_SCOPE_AGENT) < 17) {
      __builtin_amdgcn_s_sleep(8);
    }
  }
  __syncthreads();

  fftr8<false>(ZR, ZI, g_W2048, t);

  cplx* freq = (cplx*)ws + (size_t)bc * FF;
#pragma unroll
  for (int u = 0; u < 9; ++u) {
    int k = t + (u << 8);
    if (k > 2048) break;
    int ka = k & 2047, km = (2048 - k) & 2047;
    float Zkr = ZR[PHI(ka)], Zki = ZI[PHI(ka)];
    float Zmr = ZR[PHI(km)], Zmi = ZI[PHI(km)];
    float fex = 0.5f * (Zkr + Zmr);
    float fey = 0.5f * (Zki - Zmi);
    float fox = 0.5f * (Zki + Zmi);
    float foy = -0.5f * (Zkr - Zmr);
    cplx uk = g_U[k];
    float rx = fex + uk.x * fox - uk.y * foy;
    float ry = fey + uk.x * foy + uk.y * fox;
    freq[k] = make_float2(rx, ry);
    atomicAdd(&g_gi[(size_t)b * FF + k], 0.125f * sqrtf(rx * rx + ry * ry));
  }
}

// ---------------- kernel 2: K-split GEMM (1089 blocks, h-atomic)
//                  + expert irffts (2048 blocks, XCD-grouped) ----------------
__global__ __launch_bounds__(256) void k_mid(const float* __restrict__ W1,
                                             float* __restrict__ ws,
                                             float* __restrict__ out) {
  __shared__ float SM[4224];  // expert: ZR+ZI; gemm: W1s[64*33]+gis[32*33]
  const int p = blockIdx.x, t = threadIdx.x;

  if (p < 1089) {
    // ---- GEMM: h += gi @ W1^T (K-split 64, atomic into ws h) ----
    float* W1s = SM;          // [64][33]
    float* gis = SM + 2112;   // [32][33]
    const int i0 = (p % 33) * 64;
    const int il = t & 63, bg = t >> 6;
    float acc[8] = {0, 0, 0, 0, 0, 0, 0, 0};
    const int fbeg = (p / 33) * 64;
    const int fend = min(fbeg + 64, FF);
    for (int f0 = fbeg; f0 < fend; f0 += 32) {
      for (int q = t; q < 64 * 32; q += 256) {
        int r = q >> 5, cc = q & 31;
        int gi_i = i0 + r, gf = f0 + cc;
        W1s[r * 33 + cc] = (gi_i < FF && gf < FF) ? W1[(size_t)gi_i * FF + gf] : 0.f;
      }
      for (int q = t; q < 32 * 32; q += 256) {
        int bb = q >> 5, cc = q & 31;
        int gf = f0 + cc;
        gis[bb * 33 + cc] = (gf < FF) ? g_gi[(size_t)bb * FF + gf] : 0.f;
      }
      __syncthreads();
#pragma unroll 8
      for (int cc = 0; cc < 32; ++cc) {
        float wv = W1s[il * 33 + cc];
#pragma unroll
        for (int j = 0; j < 8; ++j) acc[j] += wv * gis[(bg * 8 + j) * 33 + cc];
      }
      __syncthreads();
    }
    int ii = i0 + il;
    if (ii < FF) {
#pragma unroll
      for (int j = 0; j < 8; ++j)
        atomicAdd(&ws[WS_H + (size_t)(bg * 8 + j) * FF + ii], acc[j]);
    }
    return;
  }
  if (p < 1096) return;  // pad so expert range starts at a multiple of 8

  // experts j=0..7, XCD-grouped: blk%8 == bc%8 == freq-writer XCD
  const int e   = p - 1096;           // 0..2047
  const int xcd = e & 7, s = e >> 3;  // s in [0,256)
  const int grp = s >> 3, j = s & 7;
  const int bc  = (grp << 3) | xcd;
  expert_ifft(ws, out, SM, SM + 2112, bc, j, t);
}

// ---------------- kernel 3: zero g_gi + logits + softmax + combined irfft ---
__global__ __launch_bounds__(256) void k_comb(const float* __restrict__ b1,
                                              const float* __restrict__ W2,
                                              const float* __restrict__ b2,
                                              const float* __restrict__ ws,
                                              float* __restrict__ out) {
  __shared__ float ZR[2112], ZI[2112];
  __shared__ float red[4][8];
  __shared__ float lg[8];
  __shared__ float gates_s[8];
  const int q = blockIdx.x, t = threadIdx.x;
  const int bc = q;
  const int b  = bc >> 3, c = bc & 7;
  const int lane = t & 63, wid = t >> 6;

  // zero g_gi for the next iteration (its reader, k_mid's GEMM, completed
  // at the previous kernel boundary)
  {
    int i = q * 256 + t;
    g_gi[i] = 0.f;
    if (i < 32) g_gi[65536 + i] = 0.f;  // 32*2049 = 65568
  }

  // logits for batch b (redundant across the 8 c-blocks; ~64 FMA/thread)
  float pacc[8] = {0, 0, 0, 0, 0, 0, 0, 0};
  const float* hrow = ws + WS_H + (size_t)b * FF;
  for (int f = t; f < FF; f += 256) {
    float hv = fmaxf(hrow[f] + b1[f], 0.f);
#pragma unroll
    for (int e = 0; e < 8; ++e) pacc[e] += hv * W2[(size_t)e * FF + f];
  }
#pragma unroll
  for (int off = 32; off > 0; off >>= 1) {
#pragma unroll
    for (int e = 0; e < 8; ++e) pacc[e] += __shfl_down(pacc[e], off, 64);
  }
  if (lane == 0) {
#pragma unroll
    for (int e = 0; e < 8; ++e) red[wid][e] = pacc[e];
  }
  __syncthreads();
  if (t < 8) lg[t] = red[0][t] + red[1][t] + red[2][t] + red[3][t] + b2[t];
  __syncthreads();
  if (t < 8) {
    float mx = lg[0];
#pragma unroll
    for (int r2 = 1; r2 < 8; ++r2) mx = fmaxf(mx, lg[r2]);
    float sm = 0.f;
#pragma unroll
    for (int r2 = 0; r2 < 8; ++r2) sm += expf(lg[r2] - mx);
    float g = expf(lg[t] - mx) / sm;
    gates_s[t] = g;
    if (c == 0) out[OUT_GATE + (size_t)b * 8 + t] = g;
  }
  __syncthreads();

  const cplx* freq = (const cplx*)ws + (size_t)bc * FF;
  const int*  eof  = (const int*)(ws + WS_EOF);

#pragma unroll
  for (int u = 0; u < 8; ++u) {
    int k  = t + (u << 8);
    int km = 2048 - k;
    cplx A  = freq[k];
    cplx Bv = freq[km];
    float gk = gates_s[eof[k]], gm = gates_s[eof[km]];
    A.x *= gk; A.y *= gk; Bv.x *= gm; Bv.y *= gm;
    float Px = A.x - Bv.x, Py = A.y + Bv.y;
    float Qx = A.x + Bv.x, Qy = A.y - Bv.y;
    cplx uk = g_U[k];
    float cs = uk.x, sn = -uk.y;
    float Xox = 0.5f * (cs * Px - sn * Py);
    float Xoy = 0.5f * (cs * Py + sn * Px);
    int i = PHI(scat(k));
    ZR[i] = 0.5f * Qx - Xoy;
    ZI[i] = 0.5f * Qy + Xox;
  }
  __syncthreads();

  fftr8<true>(ZR, ZI, g_W2048, t);

  const float mul = ws[WS_SIGMA + bc] * (1.0f / 2048.0f);
  const float add = ws[WS_MEAN + bc];
  nfloat2* op = (nfloat2*)(out + OUT_COMB + (size_t)bc * LL);
#pragma unroll
  for (int u = 0; u < 8; ++u) {
    int n = t + (u << 8);
    nfloat2 o;
    o.x = ZR[PHI(n)] * mul + add;
    o.y = ZI[PHI(n)] * mul + add;
    __builtin_nontemporal_store(o, op + n);
  }
}

extern "C" void kernel_launch(void* const* d_in, const int* in_sizes, int n_in,
                              void* d_out, int out_size, void* d_ws, size_t ws_size,
                              hipStream_t stream) {
  const float* x   = (const float*)d_in[0];
  const float* raw = (const float*)d_in[1];
  const float* W1  = (const float*)d_in[2];
  const float* b1  = (const float*)d_in[3];
  const float* W2  = (const float*)d_in[4];
  const float* b2  = (const float*)d_in[5];
  float* out = (float*)d_out;
  float* ws  = (float*)d_ws;

  k_fwd<<<282, 256, 0, stream>>>(x, raw, ws, out);
  k_mid<<<1096 + 2048, 256, 0, stream>>>(W1, ws, out);
  k_comb<<<256, 256, 0, stream>>>(b1, W2, b2, ws, out);
}